// Round 4
// baseline (593.665 us; speedup 1.0000x reference)
//
#include <hip/hip_runtime.h>

// Gemma2 attention, S=4096 HID=2048 NH=8 NKV=4 HD=256, causal, tanh softcap 50,
// scaling 1/16. R4: flash moved to 32x32x16 MFMA (2x FLOP per LDS read), wave
// split = S quarters (32q x 32k) then PV (q-half x d-half); P through shared
// swizzled LDS with a third barrier. Chunk-split + atomic fp32 O/l unchanged.

#define SEQ 4096
#define HIDDEN 2048
#define NHEADS 8
#define HDIM 256

typedef unsigned short u16;
typedef __attribute__((ext_vector_type(8))) __bf16 bf16x8;
typedef __attribute__((ext_vector_type(4))) float f32x4;
typedef __attribute__((ext_vector_type(16))) float f32x16;

static __device__ inline u16 f2bf(float f) {
  union { float f; unsigned u; } x; x.f = f;
  unsigned r = x.u + 0x7FFFu + ((x.u >> 16) & 1u);   // RNE
  return (u16)(r >> 16);
}
static __device__ inline float bf2f(u16 u) {
  union { unsigned u; float f; } x; x.u = ((unsigned)u) << 16;
  return x.f;
}

typedef __attribute__((address_space(1))) const unsigned int* gp_t;
typedef __attribute__((address_space(3))) unsigned int* lp_t;
static __device__ inline void load_lds16(const u16* g, u16* l) {
  __builtin_amdgcn_global_load_lds((gp_t)g, (lp_t)l, 16, 0, 0);
}

// ---------------- prep kernels ----------------

__global__ void convert_hs_kernel(const float* __restrict__ src, u16* __restrict__ dst) {
  int i = blockIdx.x * 256 + threadIdx.x;
  float4 v = ((const float4*)src)[i];
  ushort4 o;
  o.x = f2bf(v.x); o.y = f2bf(v.y); o.z = f2bf(v.z); o.w = f2bf(v.w);
  ((ushort4*)dst)[i] = o;
}

// src fp32 (K x N) -> dst bf16 (N x K), dst row stride = K (HIDDEN)
__global__ void transpose_w_kernel(const float* __restrict__ src, u16* __restrict__ dst,
                                   int K, int N) {
  __shared__ u16 tile[64][65];
  int n0 = blockIdx.x * 64, k0 = blockIdx.y * 64;
  int tid = threadIdx.x;
  for (int i = 0; i < 16; i++) {
    int idx = i * 256 + tid; int r = idx >> 6, c = idx & 63;
    tile[r][c] = f2bf(src[(size_t)(k0 + r) * N + n0 + c]);
  }
  __syncthreads();
  for (int i = 0; i < 16; i++) {
    int idx = i * 256 + tid; int r = idx >> 6, c = idx & 63;
    dst[(size_t)(n0 + r) * K + k0 + c] = tile[c][r];
  }
}

// RoPE in place on qkv[4096][4096]: q cols 0..2047, k cols 2048..3071 (12 "heads")
__global__ void rope_kernel(u16* qkv) {
  int idx = blockIdx.x * 256 + threadIdx.x;        // 4096*12*128
  int s = idx / (12 * 128);
  int rem = idx - s * (12 * 128);
  int head = rem >> 7;
  int i = rem & 127;
  float inv = __expf(-(float)i * 0.0719557841560639f);  // ln(10000)/128
  float ang = (float)s * inv;
  float sn, cs;
  sincosf(ang, &sn, &cs);
  size_t base = (size_t)s * 4096 + head * 256 + i;
  float a = bf2f(qkv[base]);
  float b = bf2f(qkv[base + 128]);
  qkv[base]       = f2bf(a * cs - b * sn);
  qkv[base + 128] = f2bf(b * cs + a * sn);
}

// qkv v-part (rows s, cols 3072+d), d in 0..1023 -> vT[d][s]
__global__ void transpose_v_kernel(const u16* __restrict__ qkv, u16* __restrict__ vT) {
  __shared__ u16 tile[64][65];
  int d0 = blockIdx.x * 64, s0 = blockIdx.y * 64;
  int tid = threadIdx.x;
  for (int i = 0; i < 16; i++) {
    int idx = i * 256 + tid; int r = idx >> 6, c = idx & 63;
    tile[r][c] = qkv[(size_t)(s0 + r) * 4096 + 3072 + d0 + c];
  }
  __syncthreads();
  for (int i = 0; i < 16; i++) {
    int idx = i * 256 + tid; int r = idx >> 6, c = idx & 63;
    vT[(size_t)(d0 + r) * 4096 + s0 + c] = tile[c][r];
  }
}

// ---------------- GEMM (m97 structure): C = A(MxK) * Bt(NxK)^T ----------------

template <bool OUT_F32>
__global__ __launch_bounds__(256, 2) void gemm_bf16_kernel(
    const u16* __restrict__ A, const u16* __restrict__ Bt, void* __restrict__ Cout,
    int M, int N, int K) {
  __shared__ __attribute__((aligned(16))) u16 As[128 * 64];
  __shared__ __attribute__((aligned(16))) u16 Bs[128 * 64];
  int tid = threadIdx.x;
  int wave = tid >> 6, lane = tid & 63;
  int lm = lane & 15, qd = lane >> 4;
  int m0 = blockIdx.y * 128, n0 = blockIdx.x * 128;
  int wm = (wave >> 1) * 64, wn = (wave & 1) * 64;

  f32x4 acc[4][4];
#pragma unroll
  for (int a = 0; a < 4; a++)
#pragma unroll
    for (int b = 0; b < 4; b++) acc[a][b] = (f32x4){0.f, 0.f, 0.f, 0.f};

  int srow = lane >> 3;           // 0..7
  int scol = (lane & 7) * 8;      // elem offset within 64-col tile

  for (int kt = 0; kt < K; kt += 64) {
    __syncthreads();
#pragma unroll
    for (int t = 0; t < 4; t++) {
      int j = wave * 4 + t;                    // 16 chunks of 8 rows
      int row = j * 8 + srow;
      load_lds16(A  + (size_t)(m0 + row) * K + kt + scol, As + j * 512);
      load_lds16(Bt + (size_t)(n0 + row) * K + kt + scol, Bs + j * 512);
    }
    __syncthreads();
#pragma unroll
    for (int kk = 0; kk < 2; kk++) {
      bf16x8 af[4], bfr[4];
#pragma unroll
      for (int mi = 0; mi < 4; mi++)
        af[mi] = *(const bf16x8*)&As[(wm + mi * 16 + lm) * 64 + kk * 32 + qd * 8];
#pragma unroll
      for (int ni = 0; ni < 4; ni++)
        bfr[ni] = *(const bf16x8*)&Bs[(wn + ni * 16 + lm) * 64 + kk * 32 + qd * 8];
#pragma unroll
      for (int mi = 0; mi < 4; mi++)
#pragma unroll
        for (int ni = 0; ni < 4; ni++)
          acc[mi][ni] = __builtin_amdgcn_mfma_f32_16x16x32_bf16(af[mi], bfr[ni],
                                                               acc[mi][ni], 0, 0, 0);
    }
  }
#pragma unroll
  for (int mi = 0; mi < 4; mi++) {
    int row = m0 + wm + mi * 16 + qd * 4;
#pragma unroll
    for (int ni = 0; ni < 4; ni++) {
      int col = n0 + wn + ni * 16 + lm;
#pragma unroll
      for (int r = 0; r < 4; r++) {
        float v = acc[mi][ni][r];
        if (OUT_F32) ((float*)Cout)[(size_t)(row + r) * N + col] = v;
        else         ((u16*)Cout)[(size_t)(row + r) * N + col] = f2bf(v);
      }
    }
  }
}

// ---------------- flash attention, 32x32x16 MFMA ----------------
// Block = (qt 64-rows, head, chunk of k-tiles). 4 waves.
// S phase : wave w computes S quarter [qhalf=w>>1][khalf=w&1] (32q x 32k),
//           A = Q in registers, B from Ks. P -> shared swizzled LDS. Barrier.
// PV phase: wave w computes O[qhalf=w>>1][dhalf=w&1] (32q x 128d),
//           A = P from LDS, B from Vs.
// Fixed-max softmax (p=exp(softcap-50)): partials additive across chunks ->
// atomicAdd fp32 O and l; normalize_kernel divides.
// LDS: Ks 64x256 (32KB), Vs 256x64 (32KB), Pl 64x64 (8KB) = 72KB -> 2 blk/CU.
// XOR-of-16B-chunk swizzles: Ks phys = c ^ (row&31); Vs/Pl phys = c ^ (row&7).

__global__ __launch_bounds__(256, 2) void flash_kernel(
    const u16* __restrict__ qkv, const u16* __restrict__ vT,
    float* __restrict__ O_acc, float* __restrict__ l_acc) {
  __shared__ __attribute__((aligned(16))) u16 Ks[64 * 256];
  __shared__ __attribute__((aligned(16))) u16 Vs[256 * 64];
  __shared__ __attribute__((aligned(16))) u16 Pl[64 * 64];

  int tid = threadIdx.x;
  int w = tid >> 6, lane = tid & 63;
  int l31 = lane & 31, hi = lane >> 5;
  int qhalf = w >> 1, kh = w & 1, dhalf = w & 1;

  // job map: head-minor, heavy chunks first. r in [0,288) per head.
  int b = blockIdx.x;                 // 0..2303
  int h = b & 7;
  int r = 287 - (b >> 3);
  int nc = 1;
  while (r >= 4 * nc * (nc + 1)) nc++;          // nc in 1..8
  int off = r - 4 * (nc - 1) * nc;
  int qt = 8 * (nc - 1) + off / nc;
  int c = off - (off / nc) * nc;
  int n = qt + 1;
  int t0 = (n * c) / nc, t1 = (n * (c + 1)) / nc;
  int kvh = h >> 1;
  int qs = qt * 64 + qhalf * 32;               // wave's global q base

  // Q A-frags (32q x 256k): 16 chunks of K=16. m=lane&31, k=hi*8+j.
  bf16x8 aq[16];
  {
    const u16* qrow = qkv + (size_t)(qs + l31) * 4096 + h * 256 + hi * 8;
#pragma unroll
    for (int kc = 0; kc < 16; kc++) aq[kc] = *(const bf16x8*)(qrow + kc * 16);
  }
  bf16x8 ones;
#pragma unroll
  for (int e = 0; e < 8; e++) ones[e] = (__bf16)1.0f;

  f32x16 ao[4];
#pragma unroll
  for (int g = 0; g < 4; g++) ao[g] = (f32x16)(0.f);
  f32x16 al = (f32x16)(0.f);

  // staging lane constants
  int vlc = (lane & 7) ^ ((lane >> 3) & 7);    // Vs logical chunk (iter-invariant)
  int vro = lane >> 3;                          // Vs row offset within 8-row window

  for (int t = t0; t < t1; t++) {
    __syncthreads();                            // prev tile's LDS reads done
    {
      const u16* Kg = qkv + (size_t)(t * 64) * 4096 + 2048 + kvh * 256;
      const u16* Vg = vT + (size_t)(kvh * 256) * 4096 + t * 64;
#pragma unroll
      for (int i = 0; i < 8; i++) {
        int kr = (w * 8 + i) * 2 + hi;          // Ks row 0..63
        int klc = l31 ^ (kr & 31);
        load_lds16(Kg + (size_t)kr * 4096 + klc * 8, Ks + (w * 8 + i) * 512);
        int vr = (w * 8 + i) * 8 + vro;         // Vs row 0..255
        load_lds16(Vg + (size_t)vr * 4096 + vlc * 8, Vs + (w * 8 + i) * 512);
      }
    }
    __syncthreads();                            // staging complete

    // S quarter: 32q x 32k, 16 MFMA
    f32x16 sacc = (f32x16)(0.f);
#pragma unroll
    for (int kc = 0; kc < 16; kc++) {
      bf16x8 bk = *(const bf16x8*)&Ks[(kh * 32 + l31) * 256 +
                                      (((kc * 2 + hi) ^ l31) << 3)];
      sacc = __builtin_amdgcn_mfma_f32_32x32x16_bf16(aq[kc], bk, sacc, 0, 0, 0);
    }

    // softcap + causal mask -> P (bf16, swizzled shared LDS)
#pragma unroll
    for (int reg = 0; reg < 16; reg++) {
      int qa = 4 * hi + 8 * (reg >> 2) + (reg & 3);   // local q in 0..31
      int q64 = qhalf * 32 + qa;
      int key64 = kh * 32 + l31;
      float x = sacc[reg] * 0.00125f;            // s*(1/16)/50
      float x2 = x * x;
      float th = x * (1.f + x2 * (-0.33333333f + x2 * 0.13333333f));
      float p = exp2f(72.134752f * (th - 1.f));  // exp(50*tanh - 50)
      if (t * 64 + key64 > qt * 64 + q64) p = 0.f;
      Pl[q64 * 64 + (((key64 >> 3) ^ (q64 & 7)) << 3) + (key64 & 7)] = f2bf(p);
    }
    __syncthreads();                            // P visible to all waves

    // PV: O[qhalf 32][dhalf 128] += P[32][64] * V[64][128]
    bf16x8 ap[4];
#pragma unroll
    for (int kc = 0; kc < 4; kc++)
      ap[kc] = *(const bf16x8*)&Pl[(qhalf * 32 + l31) * 64 +
                                   (((kc * 2 + hi) ^ (l31 & 7)) << 3)];
#pragma unroll
    for (int g = 0; g < 4; g++) {
      int dd = dhalf * 128 + g * 32 + l31;
#pragma unroll
      for (int kc = 0; kc < 4; kc++) {
        bf16x8 bv = *(const bf16x8*)&Vs[dd * 64 + (((kc * 2 + hi) ^ (l31 & 7)) << 3)];
        ao[g] = __builtin_amdgcn_mfma_f32_32x32x16_bf16(ap[kc], bv, ao[g], 0, 0, 0);
      }
    }
    if (dhalf == 0) {
#pragma unroll
      for (int kc = 0; kc < 4; kc++)
        al = __builtin_amdgcn_mfma_f32_32x32x16_bf16(ap[kc], ones, al, 0, 0, 0);
    }
  }

  // accumulate partials
#pragma unroll
  for (int g = 0; g < 4; g++) {
    int col = h * 256 + dhalf * 128 + g * 32 + l31;
#pragma unroll
    for (int reg = 0; reg < 16; reg++) {
      int q = qs + 4 * hi + 8 * (reg >> 2) + (reg & 3);
      atomicAdd(&O_acc[(size_t)q * 2048 + col], ao[g][reg]);
    }
  }
  if (dhalf == 0 && l31 == 0) {
#pragma unroll
    for (int reg = 0; reg < 16; reg++) {
      int q = qs + 4 * hi + 8 * (reg >> 2) + (reg & 3);
      atomicAdd(&l_acc[h * 4096 + q], al[reg]);
    }
  }
}

// normalize: attn_bf16 = O_acc / l
__global__ void normalize_kernel(const float* __restrict__ O, const float* __restrict__ l,
                                 u16* __restrict__ attn) {
  int g = blockIdx.x * 256 + threadIdx.x;       // 1,048,576 threads, 8 cols each
  int row = g >> 8;
  int c0 = (g & 255) << 3;
  int h = c0 >> 8;
  float inv = 1.0f / l[h * 4096 + row];
  const float4* src = (const float4*)(O + (size_t)row * 2048 + c0);
  float4 va = src[0], vb = src[1];
  ushort4 o0, o1;
  o0.x = f2bf(va.x * inv); o0.y = f2bf(va.y * inv);
  o0.z = f2bf(va.z * inv); o0.w = f2bf(va.w * inv);
  o1.x = f2bf(vb.x * inv); o1.y = f2bf(vb.y * inv);
  o1.z = f2bf(vb.z * inv); o1.w = f2bf(vb.w * inv);
  ushort4* dst = (ushort4*)(attn + (size_t)row * 2048 + c0);
  dst[0] = o0; dst[1] = o1;
}

// ---------------- launch ----------------

extern "C" void kernel_launch(void* const* d_in, const int* in_sizes, int n_in,
                              void* d_out, int out_size, void* d_ws, size_t ws_size,
                              hipStream_t stream) {
  const float* hs = (const float*)d_in[0];
  // d_in[1] attention_mask: pure causal (window 4096 never binds at S=4096)
  // d_in[2] position_ids: arange -> row index
  const float* wq = (const float*)d_in[3];
  const float* wk = (const float*)d_in[4];
  const float* wv = (const float*)d_in[5];
  const float* wo = (const float*)d_in[6];
  float* out = (float*)d_out;

  char* ws = (char*)d_ws;
  u16* hsb    = (u16*)(ws);                      // 4096x2048 bf16 (dead after QKV gemm)
  u16* wqkvT  = (u16*)(ws + 16777216);           // 4096x2048 bf16 (dead after QKV gemm)
  u16* woT    = (u16*)(ws + 33554432);           // 2048x2048 bf16
  u16* qkv    = (u16*)(ws + 41943040);           // 4096x4096 bf16
  u16* vT     = (u16*)(ws + 75497472);           // 1024x4096 bf16
  u16* attn   = (u16*)(ws + 83886080);           // 4096x2048 bf16
  float* O_acc = (float*)(ws);                   // 4096x2048 fp32, aliases hsb+wqkvT
  float* l_acc = (float*)(ws + 100663296);       // 8x4096 fp32

  convert_hs_kernel<<<8192, 256, 0, stream>>>(hs, hsb);
  transpose_w_kernel<<<dim3(32, 32), 256, 0, stream>>>(wq, wqkvT, HIDDEN, 2048);
  transpose_w_kernel<<<dim3(16, 32), 256, 0, stream>>>(wk, wqkvT + (size_t)2048 * HIDDEN, HIDDEN, 1024);
  transpose_w_kernel<<<dim3(16, 32), 256, 0, stream>>>(wv, wqkvT + (size_t)3072 * HIDDEN, HIDDEN, 1024);
  transpose_w_kernel<<<dim3(32, 32), 256, 0, stream>>>(wo, woT, HIDDEN, 2048);

  gemm_bf16_kernel<false><<<dim3(32, 32), 256, 0, stream>>>(hsb, wqkvT, qkv, 4096, 4096, 2048);
  rope_kernel<<<24576, 256, 0, stream>>>(qkv);
  transpose_v_kernel<<<dim3(16, 64), 256, 0, stream>>>(qkv, vT);

  hipMemsetAsync(O_acc, 0, (size_t)4096 * 2048 * 4, stream);   // hsb/wqkvT dead now
  hipMemsetAsync(l_acc, 0, (size_t)8 * 4096 * 4, stream);

  flash_kernel<<<2304, 256, 0, stream>>>(qkv, vT, O_acc, l_acc);
  normalize_kernel<<<4096, 256, 0, stream>>>(O_acc, l_acc, attn);
  gemm_bf16_kernel<true><<<dim3(16, 32), 256, 0, stream>>>(attn, woT, out, 4096, 2048, 2048);
}

// Round 5
// 589.566 us; speedup vs baseline: 1.0070x; 1.0070x over previous
//
#include <hip/hip_runtime.h>

// Gemma2 attention, S=4096 HID=2048 NH=8 NKV=4 HD=256, causal, tanh softcap 50,
// scaling 1/16. R5 = R4 (32x32x16 MFMA flash: S quarters, shared-P, 32q x 128d
// PV) + Q staged through LDS (coalesced 512B rows) instead of the R4 per-lane
// 32-row/16B scatter that caused the 219MB HBM fetch storm.

#define SEQ 4096
#define HIDDEN 2048
#define NHEADS 8
#define HDIM 256

typedef unsigned short u16;
typedef __attribute__((ext_vector_type(8))) __bf16 bf16x8;
typedef __attribute__((ext_vector_type(4))) float f32x4;
typedef __attribute__((ext_vector_type(16))) float f32x16;

static __device__ inline u16 f2bf(float f) {
  union { float f; unsigned u; } x; x.f = f;
  unsigned r = x.u + 0x7FFFu + ((x.u >> 16) & 1u);   // RNE
  return (u16)(r >> 16);
}
static __device__ inline float bf2f(u16 u) {
  union { unsigned u; float f; } x; x.u = ((unsigned)u) << 16;
  return x.f;
}

typedef __attribute__((address_space(1))) const unsigned int* gp_t;
typedef __attribute__((address_space(3))) unsigned int* lp_t;
static __device__ inline void load_lds16(const u16* g, u16* l) {
  __builtin_amdgcn_global_load_lds((gp_t)g, (lp_t)l, 16, 0, 0);
}

// ---------------- prep kernels ----------------

__global__ void convert_hs_kernel(const float* __restrict__ src, u16* __restrict__ dst) {
  int i = blockIdx.x * 256 + threadIdx.x;
  float4 v = ((const float4*)src)[i];
  ushort4 o;
  o.x = f2bf(v.x); o.y = f2bf(v.y); o.z = f2bf(v.z); o.w = f2bf(v.w);
  ((ushort4*)dst)[i] = o;
}

// src fp32 (K x N) -> dst bf16 (N x K), dst row stride = K (HIDDEN)
__global__ void transpose_w_kernel(const float* __restrict__ src, u16* __restrict__ dst,
                                   int K, int N) {
  __shared__ u16 tile[64][65];
  int n0 = blockIdx.x * 64, k0 = blockIdx.y * 64;
  int tid = threadIdx.x;
  for (int i = 0; i < 16; i++) {
    int idx = i * 256 + tid; int r = idx >> 6, c = idx & 63;
    tile[r][c] = f2bf(src[(size_t)(k0 + r) * N + n0 + c]);
  }
  __syncthreads();
  for (int i = 0; i < 16; i++) {
    int idx = i * 256 + tid; int r = idx >> 6, c = idx & 63;
    dst[(size_t)(n0 + r) * K + k0 + c] = tile[c][r];
  }
}

// RoPE in place on qkv[4096][4096]: q cols 0..2047, k cols 2048..3071 (12 "heads")
__global__ void rope_kernel(u16* qkv) {
  int idx = blockIdx.x * 256 + threadIdx.x;        // 4096*12*128
  int s = idx / (12 * 128);
  int rem = idx - s * (12 * 128);
  int head = rem >> 7;
  int i = rem & 127;
  float inv = __expf(-(float)i * 0.0719557841560639f);  // ln(10000)/128
  float ang = (float)s * inv;
  float sn, cs;
  sincosf(ang, &sn, &cs);
  size_t base = (size_t)s * 4096 + head * 256 + i;
  float a = bf2f(qkv[base]);
  float b = bf2f(qkv[base + 128]);
  qkv[base]       = f2bf(a * cs - b * sn);
  qkv[base + 128] = f2bf(b * cs + a * sn);
}

// qkv v-part (rows s, cols 3072+d), d in 0..1023 -> vT[d][s]
__global__ void transpose_v_kernel(const u16* __restrict__ qkv, u16* __restrict__ vT) {
  __shared__ u16 tile[64][65];
  int d0 = blockIdx.x * 64, s0 = blockIdx.y * 64;
  int tid = threadIdx.x;
  for (int i = 0; i < 16; i++) {
    int idx = i * 256 + tid; int r = idx >> 6, c = idx & 63;
    tile[r][c] = qkv[(size_t)(s0 + r) * 4096 + 3072 + d0 + c];
  }
  __syncthreads();
  for (int i = 0; i < 16; i++) {
    int idx = i * 256 + tid; int r = idx >> 6, c = idx & 63;
    vT[(size_t)(d0 + r) * 4096 + s0 + c] = tile[c][r];
  }
}

// ---------------- GEMM (m97 structure): C = A(MxK) * Bt(NxK)^T ----------------

template <bool OUT_F32>
__global__ __launch_bounds__(256, 2) void gemm_bf16_kernel(
    const u16* __restrict__ A, const u16* __restrict__ Bt, void* __restrict__ Cout,
    int M, int N, int K) {
  __shared__ __attribute__((aligned(16))) u16 As[128 * 64];
  __shared__ __attribute__((aligned(16))) u16 Bs[128 * 64];
  int tid = threadIdx.x;
  int wave = tid >> 6, lane = tid & 63;
  int lm = lane & 15, qd = lane >> 4;
  int m0 = blockIdx.y * 128, n0 = blockIdx.x * 128;
  int wm = (wave >> 1) * 64, wn = (wave & 1) * 64;

  f32x4 acc[4][4];
#pragma unroll
  for (int a = 0; a < 4; a++)
#pragma unroll
    for (int b = 0; b < 4; b++) acc[a][b] = (f32x4){0.f, 0.f, 0.f, 0.f};

  int srow = lane >> 3;           // 0..7
  int scol = (lane & 7) * 8;      // elem offset within 64-col tile

  for (int kt = 0; kt < K; kt += 64) {
    __syncthreads();
#pragma unroll
    for (int t = 0; t < 4; t++) {
      int j = wave * 4 + t;                    // 16 chunks of 8 rows
      int row = j * 8 + srow;
      load_lds16(A  + (size_t)(m0 + row) * K + kt + scol, As + j * 512);
      load_lds16(Bt + (size_t)(n0 + row) * K + kt + scol, Bs + j * 512);
    }
    __syncthreads();
#pragma unroll
    for (int kk = 0; kk < 2; kk++) {
      bf16x8 af[4], bfr[4];
#pragma unroll
      for (int mi = 0; mi < 4; mi++)
        af[mi] = *(const bf16x8*)&As[(wm + mi * 16 + lm) * 64 + kk * 32 + qd * 8];
#pragma unroll
      for (int ni = 0; ni < 4; ni++)
        bfr[ni] = *(const bf16x8*)&Bs[(wn + ni * 16 + lm) * 64 + kk * 32 + qd * 8];
#pragma unroll
      for (int mi = 0; mi < 4; mi++)
#pragma unroll
        for (int ni = 0; ni < 4; ni++)
          acc[mi][ni] = __builtin_amdgcn_mfma_f32_16x16x32_bf16(af[mi], bfr[ni],
                                                               acc[mi][ni], 0, 0, 0);
    }
  }
#pragma unroll
  for (int mi = 0; mi < 4; mi++) {
    int row = m0 + wm + mi * 16 + qd * 4;
#pragma unroll
    for (int ni = 0; ni < 4; ni++) {
      int col = n0 + wn + ni * 16 + lm;
#pragma unroll
      for (int r = 0; r < 4; r++) {
        float v = acc[mi][ni][r];
        if (OUT_F32) ((float*)Cout)[(size_t)(row + r) * N + col] = v;
        else         ((u16*)Cout)[(size_t)(row + r) * N + col] = f2bf(v);
      }
    }
  }
}

// ---------------- flash attention, 32x32x16 MFMA ----------------
// Block = (qt 64-rows, head, chunk of k-tiles). 4 waves.
// Pre-loop : Q tile staged via global_load_lds into Ks (coalesced 512B rows),
//            aq fragments read from LDS (fixes R4's 16B/32-row scatter storm).
// S phase  : wave w computes S quarter [qhalf=w>>1][khalf=w&1] (32q x 32k),
//            A = Q in registers, B from Ks. P -> shared swizzled LDS. Barrier.
// PV phase : wave w computes O[qhalf=w>>1][dhalf=w&1] (32q x 128d),
//            A = P from LDS, B from Vs.
// Fixed-max softmax (p=exp(softcap-50)): partials additive across chunks ->
// atomicAdd fp32 O and l; normalize_kernel divides.
// LDS: Ks 64x256 (32KB), Vs 256x64 (32KB), Pl 64x64 (8KB) = 72KB -> 2 blk/CU.
// XOR-of-16B-chunk swizzles: Ks phys = c ^ (row&31); Vs/Pl phys = c ^ (row&7).

__global__ __launch_bounds__(256, 2) void flash_kernel(
    const u16* __restrict__ qkv, const u16* __restrict__ vT,
    float* __restrict__ O_acc, float* __restrict__ l_acc) {
  __shared__ __attribute__((aligned(16))) u16 Ks[64 * 256];
  __shared__ __attribute__((aligned(16))) u16 Vs[256 * 64];
  __shared__ __attribute__((aligned(16))) u16 Pl[64 * 64];

  int tid = threadIdx.x;
  int w = tid >> 6, lane = tid & 63;
  int l31 = lane & 31, hi = lane >> 5;
  int qhalf = w >> 1, kh = w & 1, dhalf = w & 1;

  // job map: head-minor, heavy chunks first. r in [0,288) per head.
  int b = blockIdx.x;                 // 0..2303
  int h = b & 7;
  int r = 287 - (b >> 3);
  int nc = 1;
  while (r >= 4 * nc * (nc + 1)) nc++;          // nc in 1..8
  int off = r - 4 * (nc - 1) * nc;
  int qt = 8 * (nc - 1) + off / nc;
  int c = off - (off / nc) * nc;
  int n = qt + 1;
  int t0 = (n * c) / nc, t1 = (n * (c + 1)) / nc;
  int kvh = h >> 1;
  int qs = qt * 64 + qhalf * 32;               // wave's global q base

  // ---- stage Q tile (64 x 256) into Ks, coalesced, then read A-frags ----
  {
    const u16* Qg = qkv + (size_t)(qt * 64) * 4096 + h * 256;
#pragma unroll
    for (int i = 0; i < 8; i++) {
      int kr = (w * 8 + i) * 2 + hi;           // row 0..63
      int klc = l31 ^ (kr & 31);               // swizzled 16B chunk
      load_lds16(Qg + (size_t)kr * 4096 + klc * 8, Ks + (w * 8 + i) * 512);
    }
  }
  __syncthreads();
  // Q A-frags (32q x 256k): 16 chunks of K=16. m=lane&31, k=hi*8+j.
  bf16x8 aq[16];
#pragma unroll
  for (int kc = 0; kc < 16; kc++)
    aq[kc] = *(const bf16x8*)&Ks[(qhalf * 32 + l31) * 256 +
                                 (((kc * 2 + hi) ^ l31) << 3)];

  bf16x8 ones;
#pragma unroll
  for (int e = 0; e < 8; e++) ones[e] = (__bf16)1.0f;

  f32x16 ao[4];
#pragma unroll
  for (int g = 0; g < 4; g++) ao[g] = (f32x16)(0.f);
  f32x16 al = (f32x16)(0.f);

  // staging lane constants
  int vlc = (lane & 7) ^ ((lane >> 3) & 7);    // Vs logical chunk (iter-invariant)
  int vro = lane >> 3;                          // Vs row offset within 8-row window

  for (int t = t0; t < t1; t++) {
    __syncthreads();                            // prev tile's (or aq) LDS reads done
    {
      const u16* Kg = qkv + (size_t)(t * 64) * 4096 + 2048 + kvh * 256;
      const u16* Vg = vT + (size_t)(kvh * 256) * 4096 + t * 64;
#pragma unroll
      for (int i = 0; i < 8; i++) {
        int kr = (w * 8 + i) * 2 + hi;          // Ks row 0..63
        int klc = l31 ^ (kr & 31);
        load_lds16(Kg + (size_t)kr * 4096 + klc * 8, Ks + (w * 8 + i) * 512);
        int vr = (w * 8 + i) * 8 + vro;         // Vs row 0..255
        load_lds16(Vg + (size_t)vr * 4096 + vlc * 8, Vs + (w * 8 + i) * 512);
      }
    }
    __syncthreads();                            // staging complete

    // S quarter: 32q x 32k, 16 MFMA
    f32x16 sacc = (f32x16)(0.f);
#pragma unroll
    for (int kc = 0; kc < 16; kc++) {
      bf16x8 bk = *(const bf16x8*)&Ks[(kh * 32 + l31) * 256 +
                                      (((kc * 2 + hi) ^ l31) << 3)];
      sacc = __builtin_amdgcn_mfma_f32_32x32x16_bf16(aq[kc], bk, sacc, 0, 0, 0);
    }

    // softcap + causal mask -> P (bf16, swizzled shared LDS)
#pragma unroll
    for (int reg = 0; reg < 16; reg++) {
      int qa = 4 * hi + 8 * (reg >> 2) + (reg & 3);   // local q in 0..31
      int q64 = qhalf * 32 + qa;
      int key64 = kh * 32 + l31;
      float x = sacc[reg] * 0.00125f;            // s*(1/16)/50
      float x2 = x * x;
      float th = x * (1.f + x2 * (-0.33333333f + x2 * 0.13333333f));
      float p = exp2f(72.134752f * (th - 1.f));  // exp(50*tanh - 50)
      if (t * 64 + key64 > qt * 64 + q64) p = 0.f;
      Pl[q64 * 64 + (((key64 >> 3) ^ (q64 & 7)) << 3) + (key64 & 7)] = f2bf(p);
    }
    __syncthreads();                            // P visible to all waves

    // PV: O[qhalf 32][dhalf 128] += P[32][64] * V[64][128]
    bf16x8 ap[4];
#pragma unroll
    for (int kc = 0; kc < 4; kc++)
      ap[kc] = *(const bf16x8*)&Pl[(qhalf * 32 + l31) * 64 +
                                   (((kc * 2 + hi) ^ (l31 & 7)) << 3)];
#pragma unroll
    for (int g = 0; g < 4; g++) {
      int dd = dhalf * 128 + g * 32 + l31;
#pragma unroll
      for (int kc = 0; kc < 4; kc++) {
        bf16x8 bv = *(const bf16x8*)&Vs[dd * 64 + (((kc * 2 + hi) ^ (l31 & 7)) << 3)];
        ao[g] = __builtin_amdgcn_mfma_f32_32x32x16_bf16(ap[kc], bv, ao[g], 0, 0, 0);
      }
    }
    if (dhalf == 0) {
#pragma unroll
      for (int kc = 0; kc < 4; kc++)
        al = __builtin_amdgcn_mfma_f32_32x32x16_bf16(ap[kc], ones, al, 0, 0, 0);
    }
  }

  // accumulate partials
#pragma unroll
  for (int g = 0; g < 4; g++) {
    int col = h * 256 + dhalf * 128 + g * 32 + l31;
#pragma unroll
    for (int reg = 0; reg < 16; reg++) {
      int q = qs + 4 * hi + 8 * (reg >> 2) + (reg & 3);
      atomicAdd(&O_acc[(size_t)q * 2048 + col], ao[g][reg]);
    }
  }
  if (dhalf == 0 && l31 == 0) {
#pragma unroll
    for (int reg = 0; reg < 16; reg++) {
      int q = qs + 4 * hi + 8 * (reg >> 2) + (reg & 3);
      atomicAdd(&l_acc[h * 4096 + q], al[reg]);
    }
  }
}

// normalize: attn_bf16 = O_acc / l
__global__ void normalize_kernel(const float* __restrict__ O, const float* __restrict__ l,
                                 u16* __restrict__ attn) {
  int g = blockIdx.x * 256 + threadIdx.x;       // 1,048,576 threads, 8 cols each
  int row = g >> 8;
  int c0 = (g & 255) << 3;
  int h = c0 >> 8;
  float inv = 1.0f / l[h * 4096 + row];
  const float4* src = (const float4*)(O + (size_t)row * 2048 + c0);
  float4 va = src[0], vb = src[1];
  ushort4 o0, o1;
  o0.x = f2bf(va.x * inv); o0.y = f2bf(va.y * inv);
  o0.z = f2bf(va.z * inv); o0.w = f2bf(va.w * inv);
  o1.x = f2bf(vb.x * inv); o1.y = f2bf(vb.y * inv);
  o1.z = f2bf(vb.z * inv); o1.w = f2bf(vb.w * inv);
  ushort4* dst = (ushort4*)(attn + (size_t)row * 2048 + c0);
  dst[0] = o0; dst[1] = o1;
}

// ---------------- launch ----------------

extern "C" void kernel_launch(void* const* d_in, const int* in_sizes, int n_in,
                              void* d_out, int out_size, void* d_ws, size_t ws_size,
                              hipStream_t stream) {
  const float* hs = (const float*)d_in[0];
  // d_in[1] attention_mask: pure causal (window 4096 never binds at S=4096)
  // d_in[2] position_ids: arange -> row index
  const float* wq = (const float*)d_in[3];
  const float* wk = (const float*)d_in[4];
  const float* wv = (const float*)d_in[5];
  const float* wo = (const float*)d_in[6];
  float* out = (float*)d_out;

  char* ws = (char*)d_ws;
  u16* hsb    = (u16*)(ws);                      // 4096x2048 bf16 (dead after QKV gemm)
  u16* wqkvT  = (u16*)(ws + 16777216);           // 4096x2048 bf16 (dead after QKV gemm)
  u16* woT    = (u16*)(ws + 33554432);           // 2048x2048 bf16
  u16* qkv    = (u16*)(ws + 41943040);           // 4096x4096 bf16
  u16* vT     = (u16*)(ws + 75497472);           // 1024x4096 bf16
  u16* attn   = (u16*)(ws + 83886080);           // 4096x2048 bf16
  float* O_acc = (float*)(ws);                   // 4096x2048 fp32, aliases hsb+wqkvT
  float* l_acc = (float*)(ws + 100663296);       // 8x4096 fp32

  convert_hs_kernel<<<8192, 256, 0, stream>>>(hs, hsb);
  transpose_w_kernel<<<dim3(32, 32), 256, 0, stream>>>(wq, wqkvT, HIDDEN, 2048);
  transpose_w_kernel<<<dim3(16, 32), 256, 0, stream>>>(wk, wqkvT + (size_t)2048 * HIDDEN, HIDDEN, 1024);
  transpose_w_kernel<<<dim3(16, 32), 256, 0, stream>>>(wv, wqkvT + (size_t)3072 * HIDDEN, HIDDEN, 1024);
  transpose_w_kernel<<<dim3(32, 32), 256, 0, stream>>>(wo, woT, HIDDEN, 2048);

  gemm_bf16_kernel<false><<<dim3(32, 32), 256, 0, stream>>>(hsb, wqkvT, qkv, 4096, 4096, 2048);
  rope_kernel<<<24576, 256, 0, stream>>>(qkv);
  transpose_v_kernel<<<dim3(16, 64), 256, 0, stream>>>(qkv, vT);

  hipMemsetAsync(O_acc, 0, (size_t)4096 * 2048 * 4, stream);   // hsb/wqkvT dead now
  hipMemsetAsync(l_acc, 0, (size_t)8 * 4096 * 4, stream);

  flash_kernel<<<2304, 256, 0, stream>>>(qkv, vT, O_acc, l_acc);
  normalize_kernel<<<4096, 256, 0, stream>>>(O_acc, l_acc, attn);
  gemm_bf16_kernel<true><<<dim3(16, 32), 256, 0, stream>>>(attn, woT, out, 4096, 2048, 2048);
}

// Round 6
// 492.946 us; speedup vs baseline: 1.2043x; 1.1960x over previous
//
#include <hip/hip_runtime.h>

// Gemma2 attention, S=4096 HID=2048 NH=8 NKV=4 HD=256, causal, tanh softcap 50,
// scaling 1/16. R6: flash with perfect-balance qtile pairing (block owns qt=i
// and qt=63-i -> uniform 65 k-tiles/block, grid=256, 1 block/CU), NO atomics
// (exclusive ownership -> in-kernel normalize, bf16 store), double-buffered
// K/V staging in 136KB LDS. h=b&7 pins each XCD (blockIdx%8) to one head so
// K+V working set = 4MB = one L2. Kills the R4/R5 cross-XCD atomic ping-pong
// (489MB HBM RMW) entirely.

#define SEQ 4096
#define HIDDEN 2048
#define NHEADS 8
#define HDIM 256

typedef unsigned short u16;
typedef __attribute__((ext_vector_type(8))) __bf16 bf16x8;
typedef __attribute__((ext_vector_type(4))) float f32x4;
typedef __attribute__((ext_vector_type(16))) float f32x16;

static __device__ inline u16 f2bf(float f) {
  union { float f; unsigned u; } x; x.f = f;
  unsigned r = x.u + 0x7FFFu + ((x.u >> 16) & 1u);   // RNE
  return (u16)(r >> 16);
}
static __device__ inline float bf2f(u16 u) {
  union { unsigned u; float f; } x; x.u = ((unsigned)u) << 16;
  return x.f;
}

typedef __attribute__((address_space(1))) const unsigned int* gp_t;
typedef __attribute__((address_space(3))) unsigned int* lp_t;
static __device__ inline void load_lds16(const u16* g, u16* l) {
  __builtin_amdgcn_global_load_lds((gp_t)g, (lp_t)l, 16, 0, 0);
}

// ---------------- prep kernels ----------------

__global__ void convert_hs_kernel(const float* __restrict__ src, u16* __restrict__ dst) {
  int i = blockIdx.x * 256 + threadIdx.x;
  float4 v = ((const float4*)src)[i];
  ushort4 o;
  o.x = f2bf(v.x); o.y = f2bf(v.y); o.z = f2bf(v.z); o.w = f2bf(v.w);
  ((ushort4*)dst)[i] = o;
}

// src fp32 (K x N) -> dst bf16 (N x K), dst row stride = K (HIDDEN)
__global__ void transpose_w_kernel(const float* __restrict__ src, u16* __restrict__ dst,
                                   int K, int N) {
  __shared__ u16 tile[64][65];
  int n0 = blockIdx.x * 64, k0 = blockIdx.y * 64;
  int tid = threadIdx.x;
  for (int i = 0; i < 16; i++) {
    int idx = i * 256 + tid; int r = idx >> 6, c = idx & 63;
    tile[r][c] = f2bf(src[(size_t)(k0 + r) * N + n0 + c]);
  }
  __syncthreads();
  for (int i = 0; i < 16; i++) {
    int idx = i * 256 + tid; int r = idx >> 6, c = idx & 63;
    dst[(size_t)(n0 + r) * K + k0 + c] = tile[c][r];
  }
}

// RoPE in place on qkv[4096][4096]: q cols 0..2047, k cols 2048..3071 (12 "heads")
__global__ void rope_kernel(u16* qkv) {
  int idx = blockIdx.x * 256 + threadIdx.x;        // 4096*12*128
  int s = idx / (12 * 128);
  int rem = idx - s * (12 * 128);
  int head = rem >> 7;
  int i = rem & 127;
  float inv = __expf(-(float)i * 0.0719557841560639f);  // ln(10000)/128
  float ang = (float)s * inv;
  float sn, cs;
  sincosf(ang, &sn, &cs);
  size_t base = (size_t)s * 4096 + head * 256 + i;
  float a = bf2f(qkv[base]);
  float b = bf2f(qkv[base + 128]);
  qkv[base]       = f2bf(a * cs - b * sn);
  qkv[base + 128] = f2bf(b * cs + a * sn);
}

// qkv v-part (rows s, cols 3072+d), d in 0..1023 -> vT[d][s]
__global__ void transpose_v_kernel(const u16* __restrict__ qkv, u16* __restrict__ vT) {
  __shared__ u16 tile[64][65];
  int d0 = blockIdx.x * 64, s0 = blockIdx.y * 64;
  int tid = threadIdx.x;
  for (int i = 0; i < 16; i++) {
    int idx = i * 256 + tid; int r = idx >> 6, c = idx & 63;
    tile[r][c] = qkv[(size_t)(s0 + r) * 4096 + 3072 + d0 + c];
  }
  __syncthreads();
  for (int i = 0; i < 16; i++) {
    int idx = i * 256 + tid; int r = idx >> 6, c = idx & 63;
    vT[(size_t)(d0 + r) * 4096 + s0 + c] = tile[c][r];
  }
}

// ---------------- GEMM (m97 structure): C = A(MxK) * Bt(NxK)^T ----------------

template <bool OUT_F32>
__global__ __launch_bounds__(256, 2) void gemm_bf16_kernel(
    const u16* __restrict__ A, const u16* __restrict__ Bt, void* __restrict__ Cout,
    int M, int N, int K) {
  __shared__ __attribute__((aligned(16))) u16 As[128 * 64];
  __shared__ __attribute__((aligned(16))) u16 Bs[128 * 64];
  int tid = threadIdx.x;
  int wave = tid >> 6, lane = tid & 63;
  int lm = lane & 15, qd = lane >> 4;
  int m0 = blockIdx.y * 128, n0 = blockIdx.x * 128;
  int wm = (wave >> 1) * 64, wn = (wave & 1) * 64;

  f32x4 acc[4][4];
#pragma unroll
  for (int a = 0; a < 4; a++)
#pragma unroll
    for (int b = 0; b < 4; b++) acc[a][b] = (f32x4){0.f, 0.f, 0.f, 0.f};

  int srow = lane >> 3;           // 0..7
  int scol = (lane & 7) * 8;      // elem offset within 64-col tile

  for (int kt = 0; kt < K; kt += 64) {
    __syncthreads();
#pragma unroll
    for (int t = 0; t < 4; t++) {
      int j = wave * 4 + t;                    // 16 chunks of 8 rows
      int row = j * 8 + srow;
      load_lds16(A  + (size_t)(m0 + row) * K + kt + scol, As + j * 512);
      load_lds16(Bt + (size_t)(n0 + row) * K + kt + scol, Bs + j * 512);
    }
    __syncthreads();
#pragma unroll
    for (int kk = 0; kk < 2; kk++) {
      bf16x8 af[4], bfr[4];
#pragma unroll
      for (int mi = 0; mi < 4; mi++)
        af[mi] = *(const bf16x8*)&As[(wm + mi * 16 + lm) * 64 + kk * 32 + qd * 8];
#pragma unroll
      for (int ni = 0; ni < 4; ni++)
        bfr[ni] = *(const bf16x8*)&Bs[(wn + ni * 16 + lm) * 64 + kk * 32 + qd * 8];
#pragma unroll
      for (int mi = 0; mi < 4; mi++)
#pragma unroll
        for (int ni = 0; ni < 4; ni++)
          acc[mi][ni] = __builtin_amdgcn_mfma_f32_16x16x32_bf16(af[mi], bfr[ni],
                                                               acc[mi][ni], 0, 0, 0);
    }
  }
#pragma unroll
  for (int mi = 0; mi < 4; mi++) {
    int row = m0 + wm + mi * 16 + qd * 4;
#pragma unroll
    for (int ni = 0; ni < 4; ni++) {
      int col = n0 + wn + ni * 16 + lm;
#pragma unroll
      for (int r = 0; r < 4; r++) {
        float v = acc[mi][ni][r];
        if (OUT_F32) ((float*)Cout)[(size_t)(row + r) * N + col] = v;
        else         ((u16*)Cout)[(size_t)(row + r) * N + col] = f2bf(v);
      }
    }
  }
}

// ---------------- flash attention, paired qtiles + dbuf ----------------
// Block b: h = b&7 (XCD-affine), pair i = b>>3; segments qt=i then qt=63-i
// (i+1 + 64-i = 65 tiles -> perfect balance, exclusive ownership).
// Per segment: stage Q->Ks[0] + prefetch t0->buf1, read aq frags, then k-loop:
//   [top barrier (drains prefetch)] S(32qx32k quarters, 16 MFMA) -> softcap ->
//   P->LDS [P barrier] issue prefetch t+1 -> other buf; PV (32qx128d).
// All waves run the ones-MFMA so each holds its rows' l; epilogue divides and
// stores bf16 attn directly. No atomics, no normalize pass.
// LDS: Ks 2x32KB + Vs 2x32KB + Pl 8KB = 136KB (1 block/CU).

__global__ __launch_bounds__(256, 1) void flash_kernel(
    const u16* __restrict__ qkv, const u16* __restrict__ vT,
    u16* __restrict__ attn) {
  __shared__ __attribute__((aligned(16))) u16 Ks[2][64 * 256];
  __shared__ __attribute__((aligned(16))) u16 Vs[2][256 * 64];
  __shared__ __attribute__((aligned(16))) u16 Pl[64 * 64];

  int tid = threadIdx.x;
  int w = tid >> 6, lane = tid & 63;
  int l31 = lane & 31, hi = lane >> 5;
  int qhalf = w >> 1, kh = w & 1, dhalf = w & 1;

  int b = blockIdx.x;            // 0..255
  int h = b & 7;                 // blockIdx%8 ~ XCD id -> one head per XCD
  int pi = b >> 3;               // 0..31
  int kvh = h >> 1;

  int vlc = (lane & 7) ^ ((lane >> 3) & 7);    // V logical 16B chunk
  int vro = lane >> 3;                          // V row offset in 8-row window

  const u16* Kg  = qkv + 2048 + (size_t)kvh * 256;
  const u16* Vg0 = vT + (size_t)(kvh * 256) * 4096;

  bf16x8 ones;
#pragma unroll
  for (int e = 0; e < 8; e++) ones[e] = (__bf16)1.0f;

  for (int seg = 0; seg < 2; seg++) {
    int qt = seg ? (63 - pi) : pi;
    int T = qt + 1;
    int qs = qt * 64 + qhalf * 32;             // wave's global q base

    __syncthreads();                           // prev segment's LDS readers done
    {  // stage Q (64x256) -> Ks[0], prefetch tile 0 -> Ks[1]/Vs[1]
      const u16* Qg = qkv + (size_t)(qt * 64) * 4096 + h * 256;
#pragma unroll
      for (int s = 0; s < 8; s++) {
        int kr = (w * 8 + s) * 2 + hi;
        int klc = l31 ^ (kr & 31);
        load_lds16(Qg + (size_t)kr * 4096 + klc * 8, &Ks[0][(w * 8 + s) * 512]);
      }
#pragma unroll
      for (int s = 0; s < 8; s++) {
        int kr = (w * 8 + s) * 2 + hi;
        int klc = l31 ^ (kr & 31);
        load_lds16(Kg + (size_t)kr * 4096 + klc * 8, &Ks[1][(w * 8 + s) * 512]);
        int vr = (w * 8 + s) * 8 + vro;
        load_lds16(Vg0 + (size_t)vr * 4096 + vlc * 8, &Vs[1][(w * 8 + s) * 512]);
      }
    }
    __syncthreads();                           // Q + tile0 staged

    // Q A-frags (32q x 256k): m=lane&31, k=hi*8+j
    bf16x8 aq[16];
#pragma unroll
    for (int kc = 0; kc < 16; kc++)
      aq[kc] = *(const bf16x8*)&Ks[0][(qhalf * 32 + l31) * 256 +
                                      (((kc * 2 + hi) ^ l31) << 3)];

    f32x16 ao[4];
#pragma unroll
    for (int g = 0; g < 4; g++) ao[g] = (f32x16)(0.f);
    f32x16 al = (f32x16)(0.f);

    for (int t = 0; t < T; t++) {
      int cur = 1 - (t & 1);
      if (t > 0) __syncthreads();              // drains prefetch for this tile

      // S quarter: 32q x 32k, 16 MFMA
      f32x16 sacc = (f32x16)(0.f);
#pragma unroll
      for (int kc = 0; kc < 16; kc++) {
        bf16x8 bk = *(const bf16x8*)&Ks[cur][(kh * 32 + l31) * 256 +
                                             (((kc * 2 + hi) ^ l31) << 3)];
        sacc = __builtin_amdgcn_mfma_f32_32x32x16_bf16(aq[kc], bk, sacc, 0, 0, 0);
      }

      // softcap + causal mask -> P (bf16, swizzled shared LDS)
#pragma unroll
      for (int reg = 0; reg < 16; reg++) {
        int qa = 4 * hi + 8 * (reg >> 2) + (reg & 3);   // local q in 0..31
        int q64 = qhalf * 32 + qa;
        int key64 = kh * 32 + l31;
        float x = sacc[reg] * 0.00125f;          // s*(1/16)/50
        float x2 = x * x;
        float th = x * (1.f + x2 * (-0.33333333f + x2 * 0.13333333f));
        float p = exp2f(72.134752f * (th - 1.f));  // exp(50*tanh - 50)
        if (t * 64 + key64 > qt * 64 + q64) p = 0.f;
        Pl[q64 * 64 + (((key64 >> 3) ^ (q64 & 7)) << 3) + (key64 & 7)] = f2bf(p);
      }
      __syncthreads();                          // publish P; frees other buf

      // prefetch t+1 into the buffer not being read; in flight across PV
      if (t + 1 < T) {
        int nb = 1 - cur;
        const u16* Kt = Kg + (size_t)((t + 1) * 64) * 4096;
        const u16* Vt = Vg0 + (t + 1) * 64;
#pragma unroll
        for (int s = 0; s < 8; s++) {
          int kr = (w * 8 + s) * 2 + hi;
          int klc = l31 ^ (kr & 31);
          load_lds16(Kt + (size_t)kr * 4096 + klc * 8, &Ks[nb][(w * 8 + s) * 512]);
          int vr = (w * 8 + s) * 8 + vro;
          load_lds16(Vt + (size_t)vr * 4096 + vlc * 8, &Vs[nb][(w * 8 + s) * 512]);
        }
      }

      // PV: O[qhalf 32][dhalf 128] += P[32][64] * V[64][128]; l via ones
      bf16x8 ap[4];
#pragma unroll
      for (int kc = 0; kc < 4; kc++)
        ap[kc] = *(const bf16x8*)&Pl[(qhalf * 32 + l31) * 64 +
                                     (((kc * 2 + hi) ^ (l31 & 7)) << 3)];
#pragma unroll
      for (int g = 0; g < 4; g++) {
        int dd = dhalf * 128 + g * 32 + l31;
#pragma unroll
        for (int kc = 0; kc < 4; kc++) {
          bf16x8 bv = *(const bf16x8*)&Vs[cur][dd * 64 +
                                              (((kc * 2 + hi) ^ (l31 & 7)) << 3)];
          ao[g] = __builtin_amdgcn_mfma_f32_32x32x16_bf16(ap[kc], bv, ao[g], 0, 0, 0);
        }
      }
#pragma unroll
      for (int kc = 0; kc < 4; kc++)
        al = __builtin_amdgcn_mfma_f32_32x32x16_bf16(ap[kc], ones, al, 0, 0, 0);
    }

    // epilogue: normalize + store bf16 (exclusive rows -> plain stores)
    float inv_l[16];
#pragma unroll
    for (int reg = 0; reg < 16; reg++) inv_l[reg] = 1.f / al[reg];
#pragma unroll
    for (int g = 0; g < 4; g++) {
      int col = h * 256 + dhalf * 128 + g * 32 + l31;
#pragma unroll
      for (int reg = 0; reg < 16; reg++) {
        int row = qs + 4 * hi + 8 * (reg >> 2) + (reg & 3);
        attn[(size_t)row * 2048 + col] = f2bf(ao[g][reg] * inv_l[reg]);
      }
    }
  }
}

// ---------------- launch ----------------

extern "C" void kernel_launch(void* const* d_in, const int* in_sizes, int n_in,
                              void* d_out, int out_size, void* d_ws, size_t ws_size,
                              hipStream_t stream) {
  const float* hs = (const float*)d_in[0];
  // d_in[1] attention_mask: pure causal (window 4096 never binds at S=4096)
  // d_in[2] position_ids: arange -> row index
  const float* wq = (const float*)d_in[3];
  const float* wk = (const float*)d_in[4];
  const float* wv = (const float*)d_in[5];
  const float* wo = (const float*)d_in[6];
  float* out = (float*)d_out;

  char* ws = (char*)d_ws;
  u16* hsb    = (u16*)(ws);                      // 4096x2048 bf16
  u16* wqkvT  = (u16*)(ws + 16777216);           // 4096x2048 bf16
  u16* woT    = (u16*)(ws + 33554432);           // 2048x2048 bf16
  u16* qkv    = (u16*)(ws + 41943040);           // 4096x4096 bf16
  u16* vT     = (u16*)(ws + 75497472);           // 1024x4096 bf16
  u16* attn   = (u16*)(ws + 83886080);           // 4096x2048 bf16

  convert_hs_kernel<<<8192, 256, 0, stream>>>(hs, hsb);
  transpose_w_kernel<<<dim3(32, 32), 256, 0, stream>>>(wq, wqkvT, HIDDEN, 2048);
  transpose_w_kernel<<<dim3(16, 32), 256, 0, stream>>>(wk, wqkvT + (size_t)2048 * HIDDEN, HIDDEN, 1024);
  transpose_w_kernel<<<dim3(16, 32), 256, 0, stream>>>(wv, wqkvT + (size_t)3072 * HIDDEN, HIDDEN, 1024);
  transpose_w_kernel<<<dim3(32, 32), 256, 0, stream>>>(wo, woT, HIDDEN, 2048);

  gemm_bf16_kernel<false><<<dim3(32, 32), 256, 0, stream>>>(hsb, wqkvT, qkv, 4096, 4096, 2048);
  rope_kernel<<<24576, 256, 0, stream>>>(qkv);
  transpose_v_kernel<<<dim3(16, 64), 256, 0, stream>>>(qkv, vT);

  flash_kernel<<<256, 256, 0, stream>>>(qkv, vT, attn);
  gemm_bf16_kernel<true><<<dim3(16, 32), 256, 0, stream>>>(attn, woT, out, 4096, 2048, 2048);
}